// Round 8
// baseline (2506.355 us; speedup 1.0000x reference)
//
#include <hip/hip_runtime.h>

// R7: producer/consumer wave specialization. R6 (2300us, layer 198) showed
// neither pipe saturated (VALU 51%, fill 1.83 vs 2.9 TB/s achievable): fused
// blocks phase-oscillate. Split each block at wave boundary: waves 0-1 gather
// only, waves 2-3 GEMM only; tiles pipeline through double-buffered LDS
// (2x16KB h + 16KB mid = 48KB -> 3 blocks/CU). idx via coalesced load+shfl
// broadcast (no LDS staging). Predict: layer 198->135-160us, fill >=2.4 TB/s,
// FETCH ~250MB, total ~1700-1850us. Hang => barrier bug, revert R6.

#define N_NODES 100000
#define N_EDGES 1600000
#define HID 128
#define NUM_LAYERS 10
#define NUM_GRAPHS 64
#define SCAN_BLOCKS ((N_NODES + 255) / 256)
#define ROWS 32
#define NT (N_NODES / ROWS)   // 3125 tiles exactly
#define GRID 768              // 3 blocks/CU x 256 CU

typedef unsigned short ushort_t;

__device__ __forceinline__ float bf2f(unsigned short v) {
  return __uint_as_float(((unsigned)v) << 16);
}
__device__ __forceinline__ unsigned short f2bf(float f) {
  unsigned u = __float_as_uint(f);
  unsigned r = u + 0x7FFFu + ((u >> 16) & 1u);  // round-to-nearest-even
  return (unsigned short)(r >> 16);
}

// ---------------- CSR build ----------------

__global__ __launch_bounds__(256) void count_deg_kernel(const int* __restrict__ dst,
                                                        int* __restrict__ deg, int E) {
  int e = blockIdx.x * 256 + threadIdx.x;
  if (e < E) atomicAdd(&deg[dst[e]], 1);
}

__global__ __launch_bounds__(256) void block_sum_kernel(const int* __restrict__ deg,
                                                        int* __restrict__ psum, int n) {
  __shared__ int sd[256];
  int i = blockIdx.x * 256 + threadIdx.x;
  sd[threadIdx.x] = (i < n) ? deg[i] : 0;
  __syncthreads();
  for (int off = 128; off > 0; off >>= 1) {
    if (threadIdx.x < off) sd[threadIdx.x] += sd[threadIdx.x + off];
    __syncthreads();
  }
  if (threadIdx.x == 0) psum[blockIdx.x] = sd[0];
}

__global__ __launch_bounds__(512) void scan_partials_kernel(const int* __restrict__ psum,
                                                            int* __restrict__ poff, int nb) {
  __shared__ int sd[512];
  int i = threadIdx.x;
  int v = (i < nb) ? psum[i] : 0;
  sd[i] = v;
  __syncthreads();
  for (int off = 1; off < 512; off <<= 1) {
    int t = (i >= off) ? sd[i - off] : 0;
    __syncthreads();
    sd[i] += t;
    __syncthreads();
  }
  if (i < nb) poff[i] = sd[i] - v;  // exclusive
}

__global__ __launch_bounds__(256) void write_rs_kernel(const int* __restrict__ deg,
                                                       const int* __restrict__ poff,
                                                       int* __restrict__ rs,
                                                       int* __restrict__ cur, int n) {
  __shared__ int sd[256];
  int i = blockIdx.x * 256 + threadIdx.x;
  int v = (i < n) ? deg[i] : 0;
  sd[threadIdx.x] = v;
  __syncthreads();
  for (int off = 1; off < 256; off <<= 1) {
    int t = (threadIdx.x >= off) ? sd[threadIdx.x - off] : 0;
    __syncthreads();
    sd[threadIdx.x] += t;
    __syncthreads();
  }
  if (i < n) {
    int incl = poff[blockIdx.x] + sd[threadIdx.x];
    rs[i + 1] = incl;
    cur[i] = incl - v;
  }
  if (i == 0) rs[0] = 0;
}

__global__ __launch_bounds__(256) void fill_csr_kernel(const int* __restrict__ src,
                                                       const int* __restrict__ dst,
                                                       int* __restrict__ cur,
                                                       int* __restrict__ csr, int E) {
  int e = blockIdx.x * 256 + threadIdx.x;
  if (e < E) {
    int p = atomicAdd(&cur[dst[e]], 1);
    csr[p] = src[e];
  }
}

// one-time: bf16 shadow of the input features
__global__ __launch_bounds__(256) void cast_bf16_kernel(const float* __restrict__ xin,
                                                        ushort_t* __restrict__ xh, int n4) {
  int i = blockIdx.x * 256 + threadIdx.x;
  if (i < n4) {
    float4 v = ((const float4*)xin)[i];
    ushort4 o;
    o.x = f2bf(v.x); o.y = f2bf(v.y); o.z = f2bf(v.z); o.w = f2bf(v.w);
    ((ushort4*)xh)[i] = o;
  }
}

// gather one node row: 32-lane group, lane owns 4 cols (bf16 shadow for
// neighbors, fp32 self). Neighbor indices: lanes 0-15 coalesced-load, shfl bcast.
__device__ __forceinline__ float4 gather_row(const float4* __restrict__ x4,
                                             const ushort4* __restrict__ xh4,
                                             const int* __restrict__ rs,
                                             const int* __restrict__ csr,
                                             int node, int lane, float s) {
  float4 v = x4[node * 32 + lane];
  float ax = v.x * s, ay = v.y * s, az = v.z * s, aw = v.w * s;
  const int e0 = rs[node];
  const int m = rs[node + 1] - e0;
  int i = 0;
  while (i + 16 <= m) {
    int myi = csr[e0 + i + (lane & 15)];
    int u0 = __shfl(myi, 0, 32),  u1 = __shfl(myi, 1, 32);
    int u2 = __shfl(myi, 2, 32),  u3 = __shfl(myi, 3, 32);
    int u4 = __shfl(myi, 4, 32),  u5 = __shfl(myi, 5, 32);
    int u6 = __shfl(myi, 6, 32),  u7 = __shfl(myi, 7, 32);
    int u8 = __shfl(myi, 8, 32),  u9 = __shfl(myi, 9, 32);
    int u10 = __shfl(myi, 10, 32), u11 = __shfl(myi, 11, 32);
    int u12 = __shfl(myi, 12, 32), u13 = __shfl(myi, 13, 32);
    int u14 = __shfl(myi, 14, 32), u15 = __shfl(myi, 15, 32);
    ushort4 t0 = xh4[u0 * 32 + lane],  t1 = xh4[u1 * 32 + lane];
    ushort4 t2 = xh4[u2 * 32 + lane],  t3 = xh4[u3 * 32 + lane];
    ushort4 t4 = xh4[u4 * 32 + lane],  t5 = xh4[u5 * 32 + lane];
    ushort4 t6 = xh4[u6 * 32 + lane],  t7 = xh4[u7 * 32 + lane];
    ushort4 t8 = xh4[u8 * 32 + lane],  t9 = xh4[u9 * 32 + lane];
    ushort4 t10 = xh4[u10 * 32 + lane], t11 = xh4[u11 * 32 + lane];
    ushort4 t12 = xh4[u12 * 32 + lane], t13 = xh4[u13 * 32 + lane];
    ushort4 t14 = xh4[u14 * 32 + lane], t15 = xh4[u15 * 32 + lane];
    ax += bf2f(t0.x) + bf2f(t1.x) + bf2f(t2.x) + bf2f(t3.x)
        + bf2f(t4.x) + bf2f(t5.x) + bf2f(t6.x) + bf2f(t7.x)
        + bf2f(t8.x) + bf2f(t9.x) + bf2f(t10.x) + bf2f(t11.x)
        + bf2f(t12.x) + bf2f(t13.x) + bf2f(t14.x) + bf2f(t15.x);
    ay += bf2f(t0.y) + bf2f(t1.y) + bf2f(t2.y) + bf2f(t3.y)
        + bf2f(t4.y) + bf2f(t5.y) + bf2f(t6.y) + bf2f(t7.y)
        + bf2f(t8.y) + bf2f(t9.y) + bf2f(t10.y) + bf2f(t11.y)
        + bf2f(t12.y) + bf2f(t13.y) + bf2f(t14.y) + bf2f(t15.y);
    az += bf2f(t0.z) + bf2f(t1.z) + bf2f(t2.z) + bf2f(t3.z)
        + bf2f(t4.z) + bf2f(t5.z) + bf2f(t6.z) + bf2f(t7.z)
        + bf2f(t8.z) + bf2f(t9.z) + bf2f(t10.z) + bf2f(t11.z)
        + bf2f(t12.z) + bf2f(t13.z) + bf2f(t14.z) + bf2f(t15.z);
    aw += bf2f(t0.w) + bf2f(t1.w) + bf2f(t2.w) + bf2f(t3.w)
        + bf2f(t4.w) + bf2f(t5.w) + bf2f(t6.w) + bf2f(t7.w)
        + bf2f(t8.w) + bf2f(t9.w) + bf2f(t10.w) + bf2f(t11.w)
        + bf2f(t12.w) + bf2f(t13.w) + bf2f(t14.w) + bf2f(t15.w);
    i += 16;
  }
  int c = m - i;
  if (c) {
    int sl = (lane & 15);
    int myi = csr[e0 + i + (sl < c ? sl : 0)];
    int b = 0;
    if (c & 8) {
      int u0 = __shfl(myi, b + 0, 32), u1 = __shfl(myi, b + 1, 32);
      int u2 = __shfl(myi, b + 2, 32), u3 = __shfl(myi, b + 3, 32);
      int u4 = __shfl(myi, b + 4, 32), u5 = __shfl(myi, b + 5, 32);
      int u6 = __shfl(myi, b + 6, 32), u7 = __shfl(myi, b + 7, 32);
      ushort4 t0 = xh4[u0 * 32 + lane], t1 = xh4[u1 * 32 + lane];
      ushort4 t2 = xh4[u2 * 32 + lane], t3 = xh4[u3 * 32 + lane];
      ushort4 t4 = xh4[u4 * 32 + lane], t5 = xh4[u5 * 32 + lane];
      ushort4 t6 = xh4[u6 * 32 + lane], t7 = xh4[u7 * 32 + lane];
      ax += bf2f(t0.x) + bf2f(t1.x) + bf2f(t2.x) + bf2f(t3.x)
          + bf2f(t4.x) + bf2f(t5.x) + bf2f(t6.x) + bf2f(t7.x);
      ay += bf2f(t0.y) + bf2f(t1.y) + bf2f(t2.y) + bf2f(t3.y)
          + bf2f(t4.y) + bf2f(t5.y) + bf2f(t6.y) + bf2f(t7.y);
      az += bf2f(t0.z) + bf2f(t1.z) + bf2f(t2.z) + bf2f(t3.z)
          + bf2f(t4.z) + bf2f(t5.z) + bf2f(t6.z) + bf2f(t7.z);
      aw += bf2f(t0.w) + bf2f(t1.w) + bf2f(t2.w) + bf2f(t3.w)
          + bf2f(t4.w) + bf2f(t5.w) + bf2f(t6.w) + bf2f(t7.w);
      b += 8;
    }
    if (c & 4) {
      int u0 = __shfl(myi, b + 0, 32), u1 = __shfl(myi, b + 1, 32);
      int u2 = __shfl(myi, b + 2, 32), u3 = __shfl(myi, b + 3, 32);
      ushort4 t0 = xh4[u0 * 32 + lane], t1 = xh4[u1 * 32 + lane];
      ushort4 t2 = xh4[u2 * 32 + lane], t3 = xh4[u3 * 32 + lane];
      ax += bf2f(t0.x) + bf2f(t1.x) + bf2f(t2.x) + bf2f(t3.x);
      ay += bf2f(t0.y) + bf2f(t1.y) + bf2f(t2.y) + bf2f(t3.y);
      az += bf2f(t0.z) + bf2f(t1.z) + bf2f(t2.z) + bf2f(t3.z);
      aw += bf2f(t0.w) + bf2f(t1.w) + bf2f(t2.w) + bf2f(t3.w);
      b += 4;
    }
    if (c & 2) {
      int u0 = __shfl(myi, b + 0, 32), u1 = __shfl(myi, b + 1, 32);
      ushort4 t0 = xh4[u0 * 32 + lane], t1 = xh4[u1 * 32 + lane];
      ax += bf2f(t0.x) + bf2f(t1.x); ay += bf2f(t0.y) + bf2f(t1.y);
      az += bf2f(t0.z) + bf2f(t1.z); aw += bf2f(t0.w) + bf2f(t1.w);
      b += 2;
    }
    if (c & 1) {
      int u0 = __shfl(myi, b, 32);
      ushort4 t0 = xh4[u0 * 32 + lane];
      ax += bf2f(t0.x); ay += bf2f(t0.y); az += bf2f(t0.z); aw += bf2f(t0.w);
    }
  }
  float4 r; r.x = ax; r.y = ay; r.z = az; r.w = aw;
  return r;
}

// ---------------- fused layer: producer/consumer pipeline ----------------
// waves 0-1 (tid<128): gather tiles into lh[slot]; waves 2-3: 2-stage MLP.
// Per tile: 2 barriers. mid in separate 16KB buffer (written win1, read win2).

__global__ __launch_bounds__(256, 3) void layer_kernel(const float* __restrict__ xin,
                                                       float* __restrict__ xout,
                                                       const ushort_t* __restrict__ xh_in,
                                                       ushort_t* __restrict__ xh_out,
                                                       const int* __restrict__ rs,
                                                       const int* __restrict__ csr,
                                                       const float* __restrict__ eps, int layer,
                                                       const float* __restrict__ W1,
                                                       const float* __restrict__ b1,
                                                       const float* __restrict__ W2,
                                                       const float* __restrict__ b2,
                                                       int n, int addH) {
  __shared__ float lh[2][ROWS * 128];   // 32 KB: double-buffered h tiles
  __shared__ float lmid[ROWS * 128];    // 16 KB: mid (single slot)
  const int tid = threadIdx.x;
  const int bid = blockIdx.x;
  const float4* x4 = (const float4*)xin;
  const ushort4* xh4 = (const ushort4*)xh_in;
  const float s = 1.0f + eps[layer];

  int ntiles = 0;
  for (int t = bid; t < NT; t += GRID) ntiles++;

  const bool producer = (tid < 128);
  const int g = (tid >> 5) & 3;   // producer: group 0..3 (32 lanes each)
  const int lane = tid & 31;
  const int ctid = tid - 128;     // consumer thread id 0..127
  const int cg = ctid & 31;
  const int rg = ctid >> 5;       // 0..3 -> rows rg*8..rg*8+7

  // ---- prologue: producer gathers tile 0 fully into slot 0
  if (producer && ntiles > 0) {
    int row0 = (bid)*ROWS;
#pragma unroll
    for (int rr = 0; rr < 8; ++rr) {            // group g: rows g*8..g*8+7? no:
      int li = g + rr * 4;                       // rows g, g+4, ..., g+28 (8 rows)
      int node = row0 + li;
      if (node < n) {
        float4 h = gather_row(x4, xh4, rs, csr, node, lane, s);
        *(float4*)(&lh[0][li * 128 + lane * 4]) = h;
      }
    }
  }
  __syncthreads();

  for (int k = 0; k < ntiles; ++k) {
    const int tcur = bid + k * GRID;
    const int tnext = tcur + GRID;
    const int slot = k & 1;
    const int nslot = slot ^ 1;
    const int row0 = tcur * ROWS;

    // ---- window 1: producer gathers first half of next tile; consumer GEMM1
    if (producer) {
      if (k + 1 < ntiles) {
        int nrow0 = tnext * ROWS;
#pragma unroll
        for (int rr = 0; rr < 4; ++rr) {
          int li = g + rr * 4;                   // rows 0..15 region
          int node = nrow0 + li;
          if (node < n) {
            float4 h = gather_row(x4, xh4, rs, csr, node, lane, s);
            *(float4*)(&lh[nslot][li * 128 + lane * 4]) = h;
          }
        }
      }
    } else {
      // GEMM1: mid = relu(h@W1 + b1) into lmid
      float acc[8][4];
#pragma unroll
      for (int r = 0; r < 8; ++r) { acc[r][0] = acc[r][1] = acc[r][2] = acc[r][3] = 0.f; }
      const float* lhs = lh[slot];
      for (int k4 = 0; k4 < 32; ++k4) {
        float4 w0 = *(const float4*)(W1 + (k4 * 4 + 0) * 128 + cg * 4);
        float4 w1 = *(const float4*)(W1 + (k4 * 4 + 1) * 128 + cg * 4);
        float4 w2 = *(const float4*)(W1 + (k4 * 4 + 2) * 128 + cg * 4);
        float4 w3 = *(const float4*)(W1 + (k4 * 4 + 3) * 128 + cg * 4);
#pragma unroll
        for (int r = 0; r < 8; ++r) {
          float4 a = *(const float4*)(lhs + (rg * 8 + r) * 128 + k4 * 4);
          acc[r][0] += a.x * w0.x + a.y * w1.x + a.z * w2.x + a.w * w3.x;
          acc[r][1] += a.x * w0.y + a.y * w1.y + a.z * w2.y + a.w * w3.y;
          acc[r][2] += a.x * w0.z + a.y * w1.z + a.z * w2.z + a.w * w3.z;
          acc[r][3] += a.x * w0.w + a.y * w1.w + a.z * w2.w + a.w * w3.w;
        }
      }
      float4 bb = *(const float4*)(b1 + cg * 4);
#pragma unroll
      for (int r = 0; r < 8; ++r) {
        float4 o;
        o.x = fmaxf(acc[r][0] + bb.x, 0.f);
        o.y = fmaxf(acc[r][1] + bb.y, 0.f);
        o.z = fmaxf(acc[r][2] + bb.z, 0.f);
        o.w = fmaxf(acc[r][3] + bb.w, 0.f);
        *(float4*)(lmid + (rg * 8 + r) * 128 + cg * 4) = o;
      }
    }
    __syncthreads();

    // ---- window 2: producer gathers second half of next tile; consumer GEMM2+epilogue
    if (producer) {
      if (k + 1 < ntiles) {
        int nrow0 = tnext * ROWS;
#pragma unroll
        for (int rr = 0; rr < 4; ++rr) {
          int li = 16 + g + rr * 4;              // rows 16..31 region
          int node = nrow0 + li;
          if (node < n) {
            float4 h = gather_row(x4, xh4, rs, csr, node, lane, s);
            *(float4*)(&lh[nslot][li * 128 + lane * 4]) = h;
          }
        }
      }
    } else {
      float acc[8][4];
#pragma unroll
      for (int r = 0; r < 8; ++r) { acc[r][0] = acc[r][1] = acc[r][2] = acc[r][3] = 0.f; }
      for (int k4 = 0; k4 < 32; ++k4) {
        float4 w0 = *(const float4*)(W2 + (k4 * 4 + 0) * 128 + cg * 4);
        float4 w1 = *(const float4*)(W2 + (k4 * 4 + 1) * 128 + cg * 4);
        float4 w2 = *(const float4*)(W2 + (k4 * 4 + 2) * 128 + cg * 4);
        float4 w3 = *(const float4*)(W2 + (k4 * 4 + 3) * 128 + cg * 4);
#pragma unroll
        for (int r = 0; r < 8; ++r) {
          float4 a = *(const float4*)(lmid + (rg * 8 + r) * 128 + k4 * 4);
          acc[r][0] += a.x * w0.x + a.y * w1.x + a.z * w2.x + a.w * w3.x;
          acc[r][1] += a.x * w0.y + a.y * w1.y + a.z * w2.y + a.w * w3.y;
          acc[r][2] += a.x * w0.z + a.y * w1.z + a.z * w2.z + a.w * w3.z;
          acc[r][3] += a.x * w0.w + a.y * w1.w + a.z * w2.w + a.w * w3.w;
        }
      }
      float4 b2v = *(const float4*)(b2 + cg * 4);
      float4* xo4 = (float4*)xout;
      ushort4* xho4 = (ushort4*)xh_out;
      const float* lhs = lh[slot];
#pragma unroll
      for (int r = 0; r < 8; ++r) {
        int row = row0 + rg * 8 + r;
        if (row < n) {
          float ox = acc[r][0] + b2v.x;
          float oy = acc[r][1] + b2v.y;
          float oz = acc[r][2] + b2v.z;
          float ow = acc[r][3] + b2v.w;
          if (addH) {
            float4 hv = *(const float4*)(lhs + (rg * 8 + r) * 128 + cg * 4);
            ox += hv.x; oy += hv.y; oz += hv.z; ow += hv.w;
          }
          ox = fmaxf(ox, 0.f); oy = fmaxf(oy, 0.f); oz = fmaxf(oz, 0.f); ow = fmaxf(ow, 0.f);
          float4 xv = x4[row * 32 + cg];
          float4 o;
          o.x = ox + xv.x; o.y = oy + xv.y; o.z = oz + xv.z; o.w = ow + xv.w;
          xo4[row * 32 + cg] = o;
          ushort4 ob;
          ob.x = f2bf(o.x); ob.y = f2bf(o.y); ob.z = f2bf(o.z); ob.w = f2bf(o.w);
          xho4[row * 32 + cg] = ob;
        }
      }
    }
    __syncthreads();
  }
}

// ---------------- pooling (batch is sorted) ----------------

__global__ __launch_bounds__(128) void pool_kernel(const float* __restrict__ x,
                                                   const int* __restrict__ batch,
                                                   float* __restrict__ pool,
                                                   int* __restrict__ gcnt, int n) {
  const int CH = 512;
  int c = threadIdx.x;
  int n0 = blockIdx.x * CH;
  if (n0 >= n) return;
  int n1 = n0 + CH; if (n1 > n) n1 = n;
  float acc = 0.f;
  int g = batch[n0];
  int cl = 0;
  for (int i = n0; i < n1; ++i) {
    int gi = batch[i];
    if (gi != g) {
      atomicAdd(&pool[g * 128 + c], acc);
      if (c == 0) atomicAdd(&gcnt[g], cl);
      acc = 0.f; cl = 0; g = gi;
    }
    acc += x[i * 128 + c];
    cl++;
  }
  atomicAdd(&pool[g * 128 + c], acc);
  if (c == 0) atomicAdd(&gcnt[g], cl);
}

// ---------------- classifier: one block per graph ----------------

__global__ __launch_bounds__(128) void classifier_kernel(const float* __restrict__ pool,
                                                         const int* __restrict__ gcnt,
                                                         const float* __restrict__ Wc1,
                                                         const float* __restrict__ bc1,
                                                         const float* __restrict__ Wc2,
                                                         const float* __restrict__ bc2,
                                                         float* __restrict__ out) {
  __shared__ float prow[128];
  __shared__ float hid[128];
  int g = blockIdx.x;
  int c = threadIdx.x;
  float cf = (float)gcnt[g];
  if (cf < 1.f) cf = 1.f;
  prow[c] = pool[g * 128 + c] / cf;
  __syncthreads();
  float a = bc1[c];
  for (int k = 0; k < 128; ++k) a += prow[k] * Wc1[k * 128 + c];
  hid[c] = fmaxf(a, 0.f);
  __syncthreads();
  if (c < 2) {
    float a2 = bc2[c];
    for (int k = 0; k < 128; ++k) a2 += hid[k] * Wc2[k * 2 + c];
    out[g * 2 + c] = a2;
  }
}

// ---------------- launch ----------------

extern "C" void kernel_launch(void* const* d_in, const int* in_sizes, int n_in,
                              void* d_out, int out_size, void* d_ws, size_t ws_size,
                              hipStream_t stream) {
  const float* x_in = (const float*)d_in[0];
  const int* edge_index = (const int*)d_in[1];
  const int* batch = (const int*)d_in[2];
  const float* eps = (const float*)d_in[3];
  const float* W1 = (const float*)d_in[4];
  const float* b1 = (const float*)d_in[5];
  const float* W2 = (const float*)d_in[6];
  const float* b2 = (const float*)d_in[7];
  const float* Wc1 = (const float*)d_in[8];
  const float* bc1 = (const float*)d_in[9];
  const float* Wc2 = (const float*)d_in[10];
  const float* bc2 = (const float*)d_in[11];
  float* out = (float*)d_out;

  const int N = N_NODES, E = N_EDGES;
  const int* src = edge_index;
  const int* dst = edge_index + E;

  // workspace layout: one fp32 state + two bf16 shadows
  float* xa = (float*)d_ws;                        // N*128 floats (fp32 state, in-place)
  ushort_t* xha = (ushort_t*)(xa + (size_t)N * 128);   // N*128 bf16
  ushort_t* xhb = xha + (size_t)N * 128;               // N*128 bf16
  int* deg = (int*)(xhb + (size_t)N * 128);        // N
  int* rs = deg + N;                               // N+1
  int* cur = rs + (N + 1);                         // N
  int* csr = cur + N;                              // E
  float* pool = (float*)(csr + E);                 // 64*128
  int* gcnt = (int*)(pool + NUM_GRAPHS * 128);     // 64
  int* psum = gcnt + NUM_GRAPHS;                   // SCAN_BLOCKS
  int* poff = psum + SCAN_BLOCKS;                  // SCAN_BLOCKS

  hipMemsetAsync(deg, 0, N * sizeof(int), stream);

  // CSR build
  count_deg_kernel<<<(E + 255) / 256, 256, 0, stream>>>(dst, deg, E);
  block_sum_kernel<<<SCAN_BLOCKS, 256, 0, stream>>>(deg, psum, N);
  scan_partials_kernel<<<1, 512, 0, stream>>>(psum, poff, SCAN_BLOCKS);
  write_rs_kernel<<<SCAN_BLOCKS, 256, 0, stream>>>(deg, poff, rs, cur, N);
  fill_csr_kernel<<<(E + 255) / 256, 256, 0, stream>>>(src, dst, cur, csr, E);

  // bf16 shadow of the input
  cast_bf16_kernel<<<(N * 32 + 255) / 256, 256, 0, stream>>>(x_in, xha, N * 32);

  // layers: fp32 state in-place in xa (layer 0 reads x_in); bf16 shadow ping-pongs
  for (int i = 0; i < NUM_LAYERS; ++i) {
    const float* xi = (i == 0) ? x_in : xa;
    const ushort_t* gin = (i % 2 == 0) ? xha : xhb;
    ushort_t* gout = (i % 2 == 0) ? xhb : xha;
    layer_kernel<<<GRID, 256, 0, stream>>>(xi, xa, gin, gout, rs, csr, eps, i,
                                           W1 + (size_t)i * 128 * 128, b1 + (size_t)i * 128,
                                           W2 + (size_t)i * 128 * 128, b2 + (size_t)i * 128,
                                           N, i > 0 ? 1 : 0);
  }

  // pooling + classifier
  hipMemsetAsync(pool, 0, NUM_GRAPHS * 128 * sizeof(float), stream);
  hipMemsetAsync(gcnt, 0, NUM_GRAPHS * sizeof(int), stream);
  pool_kernel<<<(N + 511) / 512, 128, 0, stream>>>(xa, batch, pool, gcnt, N);
  classifier_kernel<<<NUM_GRAPHS, 128, 0, stream>>>(pool, gcnt, Wc1, bc1, Wc2, bc2, out);
}

// Round 9
// 2315.118 us; speedup vs baseline: 1.0826x; 1.0826x over previous
//
#include <hip/hip_runtime.h>

// R8: 1-wave-per-tile, zero cross-wave sync. R7 (static producer/consumer)
// starved memory (6 gather waves/CU, 1.24 TB/s, occ 27%). R6 fused is barrier
// phase-locked (VALU 51%, fill 1.87 vs 2.9 TB/s ceiling). Fix: block=64thr=
// 1 wave owns 8 rows; idx(1KB)+h/mid(4KB shared region) wave-private LDS;
// syncthreads in 1-wave block ~free; ~24 resident waves/CU drift freely between
// gather (mem) and GEMM (VALU) phases -> both pipes fed dynamically.
// Predict: VGPR 64-84/scratch0, occ 70-75%, layer 198->150-170us, VALU 60-65%,
// FETCH ~250MB, total ~1800-2000us. layer>=190 @ high occ => issue-rate bound.

#define N_NODES 100000
#define N_EDGES 1600000
#define HID 128
#define NUM_LAYERS 10
#define NUM_GRAPHS 64
#define SCAN_BLOCKS ((N_NODES + 255) / 256)
#define WROWS 8           // rows per wave-block; N_NODES % 8 == 0 -> 12500 blocks
#define WIDX_CAP 256      // staged neighbor indices per 8-row tile (mean 128, sigma ~11)

typedef unsigned short ushort_t;

__device__ __forceinline__ float bf2f(unsigned short v) {
  return __uint_as_float(((unsigned)v) << 16);
}
__device__ __forceinline__ unsigned short f2bf(float f) {
  unsigned u = __float_as_uint(f);
  unsigned r = u + 0x7FFFu + ((u >> 16) & 1u);  // round-to-nearest-even
  return (unsigned short)(r >> 16);
}

// ---------------- CSR build ----------------

__global__ __launch_bounds__(256) void count_deg_kernel(const int* __restrict__ dst,
                                                        int* __restrict__ deg, int E) {
  int e = blockIdx.x * 256 + threadIdx.x;
  if (e < E) atomicAdd(&deg[dst[e]], 1);
}

__global__ __launch_bounds__(256) void block_sum_kernel(const int* __restrict__ deg,
                                                        int* __restrict__ psum, int n) {
  __shared__ int sd[256];
  int i = blockIdx.x * 256 + threadIdx.x;
  sd[threadIdx.x] = (i < n) ? deg[i] : 0;
  __syncthreads();
  for (int off = 128; off > 0; off >>= 1) {
    if (threadIdx.x < off) sd[threadIdx.x] += sd[threadIdx.x + off];
    __syncthreads();
  }
  if (threadIdx.x == 0) psum[blockIdx.x] = sd[0];
}

__global__ __launch_bounds__(512) void scan_partials_kernel(const int* __restrict__ psum,
                                                            int* __restrict__ poff, int nb) {
  __shared__ int sd[512];
  int i = threadIdx.x;
  int v = (i < nb) ? psum[i] : 0;
  sd[i] = v;
  __syncthreads();
  for (int off = 1; off < 512; off <<= 1) {
    int t = (i >= off) ? sd[i - off] : 0;
    __syncthreads();
    sd[i] += t;
    __syncthreads();
  }
  if (i < nb) poff[i] = sd[i] - v;  // exclusive
}

__global__ __launch_bounds__(256) void write_rs_kernel(const int* __restrict__ deg,
                                                       const int* __restrict__ poff,
                                                       int* __restrict__ rs,
                                                       int* __restrict__ cur, int n) {
  __shared__ int sd[256];
  int i = blockIdx.x * 256 + threadIdx.x;
  int v = (i < n) ? deg[i] : 0;
  sd[threadIdx.x] = v;
  __syncthreads();
  for (int off = 1; off < 256; off <<= 1) {
    int t = (threadIdx.x >= off) ? sd[threadIdx.x - off] : 0;
    __syncthreads();
    sd[threadIdx.x] += t;
    __syncthreads();
  }
  if (i < n) {
    int incl = poff[blockIdx.x] + sd[threadIdx.x];
    rs[i + 1] = incl;
    cur[i] = incl - v;
  }
  if (i == 0) rs[0] = 0;
}

__global__ __launch_bounds__(256) void fill_csr_kernel(const int* __restrict__ src,
                                                       const int* __restrict__ dst,
                                                       int* __restrict__ cur,
                                                       int* __restrict__ csr, int E) {
  int e = blockIdx.x * 256 + threadIdx.x;
  if (e < E) {
    int p = atomicAdd(&cur[dst[e]], 1);
    csr[p] = src[e];
  }
}

// one-time: bf16 shadow of the input features
__global__ __launch_bounds__(256) void cast_bf16_kernel(const float* __restrict__ xin,
                                                        ushort_t* __restrict__ xh, int n4) {
  int i = blockIdx.x * 256 + threadIdx.x;
  if (i < n4) {
    float4 v = ((const float4*)xin)[i];
    ushort4 o;
    o.x = f2bf(v.x); o.y = f2bf(v.y); o.z = f2bf(v.z); o.w = f2bf(v.w);
    ((ushort4*)xh)[i] = o;
  }
}

// ---------------- fused layer: one independent wave per 8-row tile ----------------
// xout = relu( relu(h@W1+b1)@W2 + b2 [+h] ) + xin,  h = (1+eps)*xin + sum bf16(xin[u])
// fp32 state in-place; neighbor reads from bf16 shadow; shadow ping-pongs.
// 64-thread block = 1 wave. LDS: lbuf 4KB (h, then mid) + lidx 1KB. No cross-wave
// sync anywhere; __syncthreads in a 1-wave block is just a waitcnt-level fence.

__global__ __launch_bounds__(64, 6) void layer_kernel(const float* __restrict__ xin,
                                                      float* __restrict__ xout,
                                                      const ushort_t* __restrict__ xh_in,
                                                      ushort_t* __restrict__ xh_out,
                                                      const int* __restrict__ rs,
                                                      const int* __restrict__ csr,
                                                      const float* __restrict__ eps, int layer,
                                                      const float* __restrict__ W1,
                                                      const float* __restrict__ b1,
                                                      const float* __restrict__ W2,
                                                      const float* __restrict__ b2,
                                                      int n, int addH) {
  __shared__ float lbuf[WROWS * 128];  // 4 KB: h tile, later overwritten by mid
  __shared__ int lidx[WIDX_CAP];       // 1 KB
  const int lane = threadIdx.x;        // 0..63
  const int base = blockIdx.x * WROWS;
  const float4* x4 = (const float4*)xin;
  const ushort4* xh4 = (const ushort4*)xh_in;
  const float s = 1.0f + eps[layer];

  // ---- stage this tile's CSR index range (coalesced, 64 lanes)
  const int eBase = rs[base];
  int rowEnd = base + WROWS; if (rowEnd > n) rowEnd = n;
  const int cnt = rs[rowEnd] - eBase;
  const int stage = (cnt < WIDX_CAP) ? cnt : WIDX_CAP;
  for (int t = lane; t < stage; t += 64) lidx[t] = csr[eBase + t];
  __syncthreads();

  // ---- gather 8 rows: 2 groups of 32 lanes, 4 sequential row-pairs
  const int g = lane >> 5;      // 0/1
  const int l5 = lane & 31;     // col group within row
#pragma unroll
  for (int it = 0; it < 4; ++it) {
    int li = it * 2 + g;        // local row 0..7
    int node = base + li;
    float ax = 0.f, ay = 0.f, az = 0.f, aw = 0.f;
    if (node < n) {
      float4 v = x4[node * 32 + l5];   // self term: fp32
      ax = v.x * s; ay = v.y * s; az = v.z * s; aw = v.w * s;
      const int e0 = rs[node];
      const int m = rs[node + 1] - e0;
      const int lb = e0 - eBase;
      int i = 0;
      if (lb + m <= stage) {
        for (; i + 8 <= m; i += 8) {
          int u0 = lidx[lb + i + 0], u1 = lidx[lb + i + 1];
          int u2 = lidx[lb + i + 2], u3 = lidx[lb + i + 3];
          int u4 = lidx[lb + i + 4], u5 = lidx[lb + i + 5];
          int u6 = lidx[lb + i + 6], u7 = lidx[lb + i + 7];
          ushort4 t0 = xh4[u0 * 32 + l5];
          ushort4 t1 = xh4[u1 * 32 + l5];
          ushort4 t2 = xh4[u2 * 32 + l5];
          ushort4 t3 = xh4[u3 * 32 + l5];
          ushort4 t4 = xh4[u4 * 32 + l5];
          ushort4 t5 = xh4[u5 * 32 + l5];
          ushort4 t6 = xh4[u6 * 32 + l5];
          ushort4 t7 = xh4[u7 * 32 + l5];
          ax += bf2f(t0.x) + bf2f(t1.x) + bf2f(t2.x) + bf2f(t3.x)
              + bf2f(t4.x) + bf2f(t5.x) + bf2f(t6.x) + bf2f(t7.x);
          ay += bf2f(t0.y) + bf2f(t1.y) + bf2f(t2.y) + bf2f(t3.y)
              + bf2f(t4.y) + bf2f(t5.y) + bf2f(t6.y) + bf2f(t7.y);
          az += bf2f(t0.z) + bf2f(t1.z) + bf2f(t2.z) + bf2f(t3.z)
              + bf2f(t4.z) + bf2f(t5.z) + bf2f(t6.z) + bf2f(t7.z);
          aw += bf2f(t0.w) + bf2f(t1.w) + bf2f(t2.w) + bf2f(t3.w)
              + bf2f(t4.w) + bf2f(t5.w) + bf2f(t6.w) + bf2f(t7.w);
        }
        if (i + 4 <= m) {
          int u0 = lidx[lb + i + 0], u1 = lidx[lb + i + 1];
          int u2 = lidx[lb + i + 2], u3 = lidx[lb + i + 3];
          ushort4 t0 = xh4[u0 * 32 + l5];
          ushort4 t1 = xh4[u1 * 32 + l5];
          ushort4 t2 = xh4[u2 * 32 + l5];
          ushort4 t3 = xh4[u3 * 32 + l5];
          ax += bf2f(t0.x) + bf2f(t1.x) + bf2f(t2.x) + bf2f(t3.x);
          ay += bf2f(t0.y) + bf2f(t1.y) + bf2f(t2.y) + bf2f(t3.y);
          az += bf2f(t0.z) + bf2f(t1.z) + bf2f(t2.z) + bf2f(t3.z);
          aw += bf2f(t0.w) + bf2f(t1.w) + bf2f(t2.w) + bf2f(t3.w);
          i += 4;
        }
        if (i + 2 <= m) {
          int u0 = lidx[lb + i + 0], u1 = lidx[lb + i + 1];
          ushort4 t0 = xh4[u0 * 32 + l5];
          ushort4 t1 = xh4[u1 * 32 + l5];
          ax += bf2f(t0.x) + bf2f(t1.x); ay += bf2f(t0.y) + bf2f(t1.y);
          az += bf2f(t0.z) + bf2f(t1.z); aw += bf2f(t0.w) + bf2f(t1.w);
          i += 2;
        }
        if (i < m) {
          int u = lidx[lb + i];
          ushort4 t = xh4[u * 32 + l5];
          ax += bf2f(t.x); ay += bf2f(t.y); az += bf2f(t.z); aw += bf2f(t.w);
        }
      } else {
        // fallback (tile with extreme total degree)
        for (; i < m; ++i) {
          int u = csr[e0 + i];
          ushort4 t = xh4[u * 32 + l5];
          ax += bf2f(t.x); ay += bf2f(t.y); az += bf2f(t.z); aw += bf2f(t.w);
        }
      }
    }
    float4 r; r.x = ax; r.y = ay; r.z = az; r.w = aw;
    *(float4*)(&lbuf[li * 128 + l5 * 4]) = r;
  }
  __syncthreads();

  // ---- GEMM1: lane (rg,cg) owns rows rg*4..rg*4+3, cols cg*4..cg*4+3
  const int cg = lane & 31;
  const int rg = lane >> 5;
  float acc[4][4];
#pragma unroll
  for (int r = 0; r < 4; ++r) { acc[r][0] = acc[r][1] = acc[r][2] = acc[r][3] = 0.f; }

  for (int k4 = 0; k4 < 32; ++k4) {
    float4 w0 = *(const float4*)(W1 + (k4 * 4 + 0) * 128 + cg * 4);
    float4 w1 = *(const float4*)(W1 + (k4 * 4 + 1) * 128 + cg * 4);
    float4 w2 = *(const float4*)(W1 + (k4 * 4 + 2) * 128 + cg * 4);
    float4 w3 = *(const float4*)(W1 + (k4 * 4 + 3) * 128 + cg * 4);
#pragma unroll
    for (int r = 0; r < 4; ++r) {
      float4 a = *(const float4*)(lbuf + (rg * 4 + r) * 128 + k4 * 4);
      acc[r][0] += a.x * w0.x + a.y * w1.x + a.z * w2.x + a.w * w3.x;
      acc[r][1] += a.x * w0.y + a.y * w1.y + a.z * w2.y + a.w * w3.y;
      acc[r][2] += a.x * w0.z + a.y * w1.z + a.z * w2.z + a.w * w3.z;
      acc[r][3] += a.x * w0.w + a.y * w1.w + a.z * w2.w + a.w * w3.w;
    }
  }

  // snapshot h (epilogue needs own 4x4) before lbuf becomes mid
  float4 hsnap[4];
#pragma unroll
  for (int r = 0; r < 4; ++r) hsnap[r] = *(const float4*)(lbuf + (rg * 4 + r) * 128 + cg * 4);
  __syncthreads();

  {
    float4 bb = *(const float4*)(b1 + cg * 4);
#pragma unroll
    for (int r = 0; r < 4; ++r) {
      float4 o;
      o.x = fmaxf(acc[r][0] + bb.x, 0.f);
      o.y = fmaxf(acc[r][1] + bb.y, 0.f);
      o.z = fmaxf(acc[r][2] + bb.z, 0.f);
      o.w = fmaxf(acc[r][3] + bb.w, 0.f);
      *(float4*)(lbuf + (rg * 4 + r) * 128 + cg * 4) = o;
      acc[r][0] = acc[r][1] = acc[r][2] = acc[r][3] = 0.f;
    }
  }
  __syncthreads();

  // ---- GEMM2
  for (int k4 = 0; k4 < 32; ++k4) {
    float4 w0 = *(const float4*)(W2 + (k4 * 4 + 0) * 128 + cg * 4);
    float4 w1 = *(const float4*)(W2 + (k4 * 4 + 1) * 128 + cg * 4);
    float4 w2 = *(const float4*)(W2 + (k4 * 4 + 2) * 128 + cg * 4);
    float4 w3 = *(const float4*)(W2 + (k4 * 4 + 3) * 128 + cg * 4);
#pragma unroll
    for (int r = 0; r < 4; ++r) {
      float4 a = *(const float4*)(lbuf + (rg * 4 + r) * 128 + k4 * 4);
      acc[r][0] += a.x * w0.x + a.y * w1.x + a.z * w2.x + a.w * w3.x;
      acc[r][1] += a.x * w0.y + a.y * w1.y + a.z * w2.y + a.w * w3.y;
      acc[r][2] += a.x * w0.z + a.y * w1.z + a.z * w2.z + a.w * w3.z;
      acc[r][3] += a.x * w0.w + a.y * w1.w + a.z * w2.w + a.w * w3.w;
    }
  }

  // ---- Epilogue: +b2 (+h) -> relu -> +x; write fp32 state AND bf16 shadow
  float4 b2v = *(const float4*)(b2 + cg * 4);
  float4* xo4 = (float4*)xout;
  ushort4* xho4 = (ushort4*)xh_out;
#pragma unroll
  for (int r = 0; r < 4; ++r) {
    int row = base + rg * 4 + r;
    if (row < n) {
      float ox = acc[r][0] + b2v.x;
      float oy = acc[r][1] + b2v.y;
      float oz = acc[r][2] + b2v.z;
      float ow = acc[r][3] + b2v.w;
      if (addH) {
        ox += hsnap[r].x; oy += hsnap[r].y; oz += hsnap[r].z; ow += hsnap[r].w;
      }
      ox = fmaxf(ox, 0.f); oy = fmaxf(oy, 0.f); oz = fmaxf(oz, 0.f); ow = fmaxf(ow, 0.f);
      float4 xv = x4[row * 32 + cg];
      float4 o;
      o.x = ox + xv.x; o.y = oy + xv.y; o.z = oz + xv.z; o.w = ow + xv.w;
      xo4[row * 32 + cg] = o;
      ushort4 ob;
      ob.x = f2bf(o.x); ob.y = f2bf(o.y); ob.z = f2bf(o.z); ob.w = f2bf(o.w);
      xho4[row * 32 + cg] = ob;
    }
  }
}

// ---------------- pooling (batch is sorted) ----------------

__global__ __launch_bounds__(128) void pool_kernel(const float* __restrict__ x,
                                                   const int* __restrict__ batch,
                                                   float* __restrict__ pool,
                                                   int* __restrict__ gcnt, int n) {
  const int CH = 512;
  int c = threadIdx.x;
  int n0 = blockIdx.x * CH;
  if (n0 >= n) return;
  int n1 = n0 + CH; if (n1 > n) n1 = n;
  float acc = 0.f;
  int g = batch[n0];
  int cl = 0;
  for (int i = n0; i < n1; ++i) {
    int gi = batch[i];
    if (gi != g) {
      atomicAdd(&pool[g * 128 + c], acc);
      if (c == 0) atomicAdd(&gcnt[g], cl);
      acc = 0.f; cl = 0; g = gi;
    }
    acc += x[i * 128 + c];
    cl++;
  }
  atomicAdd(&pool[g * 128 + c], acc);
  if (c == 0) atomicAdd(&gcnt[g], cl);
}

// ---------------- classifier: one block per graph ----------------

__global__ __launch_bounds__(128) void classifier_kernel(const float* __restrict__ pool,
                                                         const int* __restrict__ gcnt,
                                                         const float* __restrict__ Wc1,
                                                         const float* __restrict__ bc1,
                                                         const float* __restrict__ Wc2,
                                                         const float* __restrict__ bc2,
                                                         float* __restrict__ out) {
  __shared__ float prow[128];
  __shared__ float hid[128];
  int g = blockIdx.x;
  int c = threadIdx.x;
  float cf = (float)gcnt[g];
  if (cf < 1.f) cf = 1.f;
  prow[c] = pool[g * 128 + c] / cf;
  __syncthreads();
  float a = bc1[c];
  for (int k = 0; k < 128; ++k) a += prow[k] * Wc1[k * 128 + c];
  hid[c] = fmaxf(a, 0.f);
  __syncthreads();
  if (c < 2) {
    float a2 = bc2[c];
    for (int k = 0; k < 128; ++k) a2 += hid[k] * Wc2[k * 2 + c];
    out[g * 2 + c] = a2;
  }
}

// ---------------- launch ----------------

extern "C" void kernel_launch(void* const* d_in, const int* in_sizes, int n_in,
                              void* d_out, int out_size, void* d_ws, size_t ws_size,
                              hipStream_t stream) {
  const float* x_in = (const float*)d_in[0];
  const int* edge_index = (const int*)d_in[1];
  const int* batch = (const int*)d_in[2];
  const float* eps = (const float*)d_in[3];
  const float* W1 = (const float*)d_in[4];
  const float* b1 = (const float*)d_in[5];
  const float* W2 = (const float*)d_in[6];
  const float* b2 = (const float*)d_in[7];
  const float* Wc1 = (const float*)d_in[8];
  const float* bc1 = (const float*)d_in[9];
  const float* Wc2 = (const float*)d_in[10];
  const float* bc2 = (const float*)d_in[11];
  float* out = (float*)d_out;

  const int N = N_NODES, E = N_EDGES;
  const int* src = edge_index;
  const int* dst = edge_index + E;

  // workspace layout: one fp32 state + two bf16 shadows
  float* xa = (float*)d_ws;                        // N*128 floats (fp32 state, in-place)
  ushort_t* xha = (ushort_t*)(xa + (size_t)N * 128);   // N*128 bf16
  ushort_t* xhb = xha + (size_t)N * 128;               // N*128 bf16
  int* deg = (int*)(xhb + (size_t)N * 128);        // N
  int* rs = deg + N;                               // N+1
  int* cur = rs + (N + 1);                         // N
  int* csr = cur + N;                              // E
  float* pool = (float*)(csr + E);                 // 64*128
  int* gcnt = (int*)(pool + NUM_GRAPHS * 128);     // 64
  int* psum = gcnt + NUM_GRAPHS;                   // SCAN_BLOCKS
  int* poff = psum + SCAN_BLOCKS;                  // SCAN_BLOCKS

  hipMemsetAsync(deg, 0, N * sizeof(int), stream);

  // CSR build
  count_deg_kernel<<<(E + 255) / 256, 256, 0, stream>>>(dst, deg, E);
  block_sum_kernel<<<SCAN_BLOCKS, 256, 0, stream>>>(deg, psum, N);
  scan_partials_kernel<<<1, 512, 0, stream>>>(psum, poff, SCAN_BLOCKS);
  write_rs_kernel<<<SCAN_BLOCKS, 256, 0, stream>>>(deg, poff, rs, cur, N);
  fill_csr_kernel<<<(E + 255) / 256, 256, 0, stream>>>(src, dst, cur, csr, E);

  // bf16 shadow of the input
  cast_bf16_kernel<<<(N * 32 + 255) / 256, 256, 0, stream>>>(x_in, xha, N * 32);

  // layers: fp32 state in-place in xa (layer 0 reads input buffer); shadow ping-pongs
  const int NB = N / WROWS;  // 12500 one-wave blocks
  for (int i = 0; i < NUM_LAYERS; ++i) {
    const float* xi = (i == 0) ? x_in : xa;
    const ushort_t* gin = (i % 2 == 0) ? xha : xhb;
    ushort_t* gout = (i % 2 == 0) ? xhb : xha;
    layer_kernel<<<NB, 64, 0, stream>>>(xi, xa, gin, gout, rs, csr, eps, i,
                                        W1 + (size_t)i * 128 * 128, b1 + (size_t)i * 128,
                                        W2 + (size_t)i * 128 * 128, b2 + (size_t)i * 128,
                                        N, i > 0 ? 1 : 0);
  }

  // pooling + classifier
  hipMemsetAsync(pool, 0, NUM_GRAPHS * 128 * sizeof(float), stream);
  hipMemsetAsync(gcnt, 0, NUM_GRAPHS * sizeof(int), stream);
  pool_kernel<<<(N + 511) / 512, 128, 0, stream>>>(xa, batch, pool, gcnt, N);
  classifier_kernel<<<NUM_GRAPHS, 128, 0, stream>>>(pool, gcnt, Wc1, bc1, Wc2, bc2, out);
}

// Round 10
// 2246.036 us; speedup vs baseline: 1.1159x; 1.0308x over previous
//
#include <hip/hip_runtime.h>

// R9: 16-deep gather ILP. R8 proved wave topology irrelevant (R6=R8=~200us,
// fill 1.86 TB/s; pure gather 2.9). Binding knob = per-wave outstanding loads
// (Little's law): R5's VGPR-32 crush (fewer in-flight loads) regressed, so
// depth matters. Double batch 8->16 neighbor rows (8KB/wave in flight).
// VGPR 40->~72 within 85 cap at (64,6). Predict: VGPR 64-80 scratch 0, occ ~55,
// FETCH ~253MB, fill ->2.2-2.6, layer 201->160-180us, total ~1900-2050us.
// If layer ~200 unchanged: per-CU vmem queue saturated -> structural roofline.

#define N_NODES 100000
#define N_EDGES 1600000
#define HID 128
#define NUM_LAYERS 10
#define NUM_GRAPHS 64
#define SCAN_BLOCKS ((N_NODES + 255) / 256)
#define WROWS 8           // rows per wave-block; N_NODES % 8 == 0 -> 12500 blocks
#define WIDX_CAP 256      // staged neighbor indices per 8-row tile (mean 128, sigma ~11)

typedef unsigned short ushort_t;

__device__ __forceinline__ float bf2f(unsigned short v) {
  return __uint_as_float(((unsigned)v) << 16);
}
__device__ __forceinline__ unsigned short f2bf(float f) {
  unsigned u = __float_as_uint(f);
  unsigned r = u + 0x7FFFu + ((u >> 16) & 1u);  // round-to-nearest-even
  return (unsigned short)(r >> 16);
}

// ---------------- CSR build ----------------

__global__ __launch_bounds__(256) void count_deg_kernel(const int* __restrict__ dst,
                                                        int* __restrict__ deg, int E) {
  int e = blockIdx.x * 256 + threadIdx.x;
  if (e < E) atomicAdd(&deg[dst[e]], 1);
}

__global__ __launch_bounds__(256) void block_sum_kernel(const int* __restrict__ deg,
                                                        int* __restrict__ psum, int n) {
  __shared__ int sd[256];
  int i = blockIdx.x * 256 + threadIdx.x;
  sd[threadIdx.x] = (i < n) ? deg[i] : 0;
  __syncthreads();
  for (int off = 128; off > 0; off >>= 1) {
    if (threadIdx.x < off) sd[threadIdx.x] += sd[threadIdx.x + off];
    __syncthreads();
  }
  if (threadIdx.x == 0) psum[blockIdx.x] = sd[0];
}

__global__ __launch_bounds__(512) void scan_partials_kernel(const int* __restrict__ psum,
                                                            int* __restrict__ poff, int nb) {
  __shared__ int sd[512];
  int i = threadIdx.x;
  int v = (i < nb) ? psum[i] : 0;
  sd[i] = v;
  __syncthreads();
  for (int off = 1; off < 512; off <<= 1) {
    int t = (i >= off) ? sd[i - off] : 0;
    __syncthreads();
    sd[i] += t;
    __syncthreads();
  }
  if (i < nb) poff[i] = sd[i] - v;  // exclusive
}

__global__ __launch_bounds__(256) void write_rs_kernel(const int* __restrict__ deg,
                                                       const int* __restrict__ poff,
                                                       int* __restrict__ rs,
                                                       int* __restrict__ cur, int n) {
  __shared__ int sd[256];
  int i = blockIdx.x * 256 + threadIdx.x;
  int v = (i < n) ? deg[i] : 0;
  sd[threadIdx.x] = v;
  __syncthreads();
  for (int off = 1; off < 256; off <<= 1) {
    int t = (threadIdx.x >= off) ? sd[threadIdx.x - off] : 0;
    __syncthreads();
    sd[threadIdx.x] += t;
    __syncthreads();
  }
  if (i < n) {
    int incl = poff[blockIdx.x] + sd[threadIdx.x];
    rs[i + 1] = incl;
    cur[i] = incl - v;
  }
  if (i == 0) rs[0] = 0;
}

__global__ __launch_bounds__(256) void fill_csr_kernel(const int* __restrict__ src,
                                                       const int* __restrict__ dst,
                                                       int* __restrict__ cur,
                                                       int* __restrict__ csr, int E) {
  int e = blockIdx.x * 256 + threadIdx.x;
  if (e < E) {
    int p = atomicAdd(&cur[dst[e]], 1);
    csr[p] = src[e];
  }
}

// one-time: bf16 shadow of the input features
__global__ __launch_bounds__(256) void cast_bf16_kernel(const float* __restrict__ xin,
                                                        ushort_t* __restrict__ xh, int n4) {
  int i = blockIdx.x * 256 + threadIdx.x;
  if (i < n4) {
    float4 v = ((const float4*)xin)[i];
    ushort4 o;
    o.x = f2bf(v.x); o.y = f2bf(v.y); o.z = f2bf(v.z); o.w = f2bf(v.w);
    ((ushort4*)xh)[i] = o;
  }
}

// ---------------- fused layer: one independent wave per 8-row tile ----------------
// xout = relu( relu(h@W1+b1)@W2 + b2 [+h] ) + xin,  h = (1+eps)*xin + sum bf16(xin[u])
// 64-thread block = 1 wave. Gather batches 16 neighbor-row loads in flight.

__global__ __launch_bounds__(64, 6) void layer_kernel(const float* __restrict__ xin,
                                                      float* __restrict__ xout,
                                                      const ushort_t* __restrict__ xh_in,
                                                      ushort_t* __restrict__ xh_out,
                                                      const int* __restrict__ rs,
                                                      const int* __restrict__ csr,
                                                      const float* __restrict__ eps, int layer,
                                                      const float* __restrict__ W1,
                                                      const float* __restrict__ b1,
                                                      const float* __restrict__ W2,
                                                      const float* __restrict__ b2,
                                                      int n, int addH) {
  __shared__ float lbuf[WROWS * 128];  // 4 KB: h tile, later overwritten by mid
  __shared__ int lidx[WIDX_CAP];       // 1 KB
  const int lane = threadIdx.x;        // 0..63
  const int base = blockIdx.x * WROWS;
  const float4* x4 = (const float4*)xin;
  const ushort4* xh4 = (const ushort4*)xh_in;
  const float s = 1.0f + eps[layer];

  // ---- stage this tile's CSR index range (coalesced, 64 lanes)
  const int eBase = rs[base];
  int rowEnd = base + WROWS; if (rowEnd > n) rowEnd = n;
  const int cnt = rs[rowEnd] - eBase;
  const int stage = (cnt < WIDX_CAP) ? cnt : WIDX_CAP;
  for (int t = lane; t < stage; t += 64) lidx[t] = csr[eBase + t];
  __syncthreads();

  // ---- gather 8 rows: 2 groups of 32 lanes, 4 sequential row-pairs.
  // 16 neighbor-row loads in flight per batch (8 KB/wave outstanding).
  const int g = lane >> 5;      // 0/1
  const int l5 = lane & 31;     // col group within row
#pragma unroll
  for (int it = 0; it < 4; ++it) {
    int li = it * 2 + g;        // local row 0..7
    int node = base + li;
    float ax = 0.f, ay = 0.f, az = 0.f, aw = 0.f;
    if (node < n) {
      float4 v = x4[node * 32 + l5];   // self term: fp32
      ax = v.x * s; ay = v.y * s; az = v.z * s; aw = v.w * s;
      const int e0 = rs[node];
      const int m = rs[node + 1] - e0;
      const int lb = e0 - eBase;
      int i = 0;
      if (lb + m <= stage) {
        for (; i + 16 <= m; i += 16) {
          int u0 = lidx[lb + i + 0],  u1 = lidx[lb + i + 1];
          int u2 = lidx[lb + i + 2],  u3 = lidx[lb + i + 3];
          int u4 = lidx[lb + i + 4],  u5 = lidx[lb + i + 5];
          int u6 = lidx[lb + i + 6],  u7 = lidx[lb + i + 7];
          int u8 = lidx[lb + i + 8],  u9 = lidx[lb + i + 9];
          int u10 = lidx[lb + i + 10], u11 = lidx[lb + i + 11];
          int u12 = lidx[lb + i + 12], u13 = lidx[lb + i + 13];
          int u14 = lidx[lb + i + 14], u15 = lidx[lb + i + 15];
          ushort4 t0 = xh4[u0 * 32 + l5];
          ushort4 t1 = xh4[u1 * 32 + l5];
          ushort4 t2 = xh4[u2 * 32 + l5];
          ushort4 t3 = xh4[u3 * 32 + l5];
          ushort4 t4 = xh4[u4 * 32 + l5];
          ushort4 t5 = xh4[u5 * 32 + l5];
          ushort4 t6 = xh4[u6 * 32 + l5];
          ushort4 t7 = xh4[u7 * 32 + l5];
          ushort4 t8 = xh4[u8 * 32 + l5];
          ushort4 t9 = xh4[u9 * 32 + l5];
          ushort4 t10 = xh4[u10 * 32 + l5];
          ushort4 t11 = xh4[u11 * 32 + l5];
          ushort4 t12 = xh4[u12 * 32 + l5];
          ushort4 t13 = xh4[u13 * 32 + l5];
          ushort4 t14 = xh4[u14 * 32 + l5];
          ushort4 t15 = xh4[u15 * 32 + l5];
          ax += bf2f(t0.x) + bf2f(t1.x) + bf2f(t2.x) + bf2f(t3.x)
              + bf2f(t4.x) + bf2f(t5.x) + bf2f(t6.x) + bf2f(t7.x)
              + bf2f(t8.x) + bf2f(t9.x) + bf2f(t10.x) + bf2f(t11.x)
              + bf2f(t12.x) + bf2f(t13.x) + bf2f(t14.x) + bf2f(t15.x);
          ay += bf2f(t0.y) + bf2f(t1.y) + bf2f(t2.y) + bf2f(t3.y)
              + bf2f(t4.y) + bf2f(t5.y) + bf2f(t6.y) + bf2f(t7.y)
              + bf2f(t8.y) + bf2f(t9.y) + bf2f(t10.y) + bf2f(t11.y)
              + bf2f(t12.y) + bf2f(t13.y) + bf2f(t14.y) + bf2f(t15.y);
          az += bf2f(t0.z) + bf2f(t1.z) + bf2f(t2.z) + bf2f(t3.z)
              + bf2f(t4.z) + bf2f(t5.z) + bf2f(t6.z) + bf2f(t7.z)
              + bf2f(t8.z) + bf2f(t9.z) + bf2f(t10.z) + bf2f(t11.z)
              + bf2f(t12.z) + bf2f(t13.z) + bf2f(t14.z) + bf2f(t15.z);
          aw += bf2f(t0.w) + bf2f(t1.w) + bf2f(t2.w) + bf2f(t3.w)
              + bf2f(t4.w) + bf2f(t5.w) + bf2f(t6.w) + bf2f(t7.w)
              + bf2f(t8.w) + bf2f(t9.w) + bf2f(t10.w) + bf2f(t11.w)
              + bf2f(t12.w) + bf2f(t13.w) + bf2f(t14.w) + bf2f(t15.w);
        }
        if (i + 8 <= m) {
          int u0 = lidx[lb + i + 0], u1 = lidx[lb + i + 1];
          int u2 = lidx[lb + i + 2], u3 = lidx[lb + i + 3];
          int u4 = lidx[lb + i + 4], u5 = lidx[lb + i + 5];
          int u6 = lidx[lb + i + 6], u7 = lidx[lb + i + 7];
          ushort4 t0 = xh4[u0 * 32 + l5];
          ushort4 t1 = xh4[u1 * 32 + l5];
          ushort4 t2 = xh4[u2 * 32 + l5];
          ushort4 t3 = xh4[u3 * 32 + l5];
          ushort4 t4 = xh4[u4 * 32 + l5];
          ushort4 t5 = xh4[u5 * 32 + l5];
          ushort4 t6 = xh4[u6 * 32 + l5];
          ushort4 t7 = xh4[u7 * 32 + l5];
          ax += bf2f(t0.x) + bf2f(t1.x) + bf2f(t2.x) + bf2f(t3.x)
              + bf2f(t4.x) + bf2f(t5.x) + bf2f(t6.x) + bf2f(t7.x);
          ay += bf2f(t0.y) + bf2f(t1.y) + bf2f(t2.y) + bf2f(t3.y)
              + bf2f(t4.y) + bf2f(t5.y) + bf2f(t6.y) + bf2f(t7.y);
          az += bf2f(t0.z) + bf2f(t1.z) + bf2f(t2.z) + bf2f(t3.z)
              + bf2f(t4.z) + bf2f(t5.z) + bf2f(t6.z) + bf2f(t7.z);
          aw += bf2f(t0.w) + bf2f(t1.w) + bf2f(t2.w) + bf2f(t3.w)
              + bf2f(t4.w) + bf2f(t5.w) + bf2f(t6.w) + bf2f(t7.w);
          i += 8;
        }
        if (i + 4 <= m) {
          int u0 = lidx[lb + i + 0], u1 = lidx[lb + i + 1];
          int u2 = lidx[lb + i + 2], u3 = lidx[lb + i + 3];
          ushort4 t0 = xh4[u0 * 32 + l5];
          ushort4 t1 = xh4[u1 * 32 + l5];
          ushort4 t2 = xh4[u2 * 32 + l5];
          ushort4 t3 = xh4[u3 * 32 + l5];
          ax += bf2f(t0.x) + bf2f(t1.x) + bf2f(t2.x) + bf2f(t3.x);
          ay += bf2f(t0.y) + bf2f(t1.y) + bf2f(t2.y) + bf2f(t3.y);
          az += bf2f(t0.z) + bf2f(t1.z) + bf2f(t2.z) + bf2f(t3.z);
          aw += bf2f(t0.w) + bf2f(t1.w) + bf2f(t2.w) + bf2f(t3.w);
          i += 4;
        }
        if (i + 2 <= m) {
          int u0 = lidx[lb + i + 0], u1 = lidx[lb + i + 1];
          ushort4 t0 = xh4[u0 * 32 + l5];
          ushort4 t1 = xh4[u1 * 32 + l5];
          ax += bf2f(t0.x) + bf2f(t1.x); ay += bf2f(t0.y) + bf2f(t1.y);
          az += bf2f(t0.z) + bf2f(t1.z); aw += bf2f(t0.w) + bf2f(t1.w);
          i += 2;
        }
        if (i < m) {
          int u = lidx[lb + i];
          ushort4 t = xh4[u * 32 + l5];
          ax += bf2f(t.x); ay += bf2f(t.y); az += bf2f(t.z); aw += bf2f(t.w);
        }
      } else {
        // fallback (tile with extreme total degree)
        for (; i < m; ++i) {
          int u = csr[e0 + i];
          ushort4 t = xh4[u * 32 + l5];
          ax += bf2f(t.x); ay += bf2f(t.y); az += bf2f(t.z); aw += bf2f(t.w);
        }
      }
    }
    float4 r; r.x = ax; r.y = ay; r.z = az; r.w = aw;
    *(float4*)(&lbuf[li * 128 + l5 * 4]) = r;
  }
  __syncthreads();

  // ---- GEMM1: lane (rg,cg) owns rows rg*4..rg*4+3, cols cg*4..cg*4+3
  const int cg = lane & 31;
  const int rg = lane >> 5;
  float acc[4][4];
#pragma unroll
  for (int r = 0; r < 4; ++r) { acc[r][0] = acc[r][1] = acc[r][2] = acc[r][3] = 0.f; }

  for (int k4 = 0; k4 < 32; ++k4) {
    float4 w0 = *(const float4*)(W1 + (k4 * 4 + 0) * 128 + cg * 4);
    float4 w1 = *(const float4*)(W1 + (k4 * 4 + 1) * 128 + cg * 4);
    float4 w2 = *(const float4*)(W1 + (k4 * 4 + 2) * 128 + cg * 4);
    float4 w3 = *(const float4*)(W1 + (k4 * 4 + 3) * 128 + cg * 4);
#pragma unroll
    for (int r = 0; r < 4; ++r) {
      float4 a = *(const float4*)(lbuf + (rg * 4 + r) * 128 + k4 * 4);
      acc[r][0] += a.x * w0.x + a.y * w1.x + a.z * w2.x + a.w * w3.x;
      acc[r][1] += a.x * w0.y + a.y * w1.y + a.z * w2.y + a.w * w3.y;
      acc[r][2] += a.x * w0.z + a.y * w1.z + a.z * w2.z + a.w * w3.z;
      acc[r][3] += a.x * w0.w + a.y * w1.w + a.z * w2.w + a.w * w3.w;
    }
  }

  // snapshot h (epilogue needs own 4x4) before lbuf becomes mid
  float4 hsnap[4];
#pragma unroll
  for (int r = 0; r < 4; ++r) hsnap[r] = *(const float4*)(lbuf + (rg * 4 + r) * 128 + cg * 4);
  __syncthreads();

  {
    float4 bb = *(const float4*)(b1 + cg * 4);
#pragma unroll
    for (int r = 0; r < 4; ++r) {
      float4 o;
      o.x = fmaxf(acc[r][0] + bb.x, 0.f);
      o.y = fmaxf(acc[r][1] + bb.y, 0.f);
      o.z = fmaxf(acc[r][2] + bb.z, 0.f);
      o.w = fmaxf(acc[r][3] + bb.w, 0.f);
      *(float4*)(lbuf + (rg * 4 + r) * 128 + cg * 4) = o;
      acc[r][0] = acc[r][1] = acc[r][2] = acc[r][3] = 0.f;
    }
  }
  __syncthreads();

  // ---- GEMM2
  for (int k4 = 0; k4 < 32; ++k4) {
    float4 w0 = *(const float4*)(W2 + (k4 * 4 + 0) * 128 + cg * 4);
    float4 w1 = *(const float4*)(W2 + (k4 * 4 + 1) * 128 + cg * 4);
    float4 w2 = *(const float4*)(W2 + (k4 * 4 + 2) * 128 + cg * 4);
    float4 w3 = *(const float4*)(W2 + (k4 * 4 + 3) * 128 + cg * 4);
#pragma unroll
    for (int r = 0; r < 4; ++r) {
      float4 a = *(const float4*)(lbuf + (rg * 4 + r) * 128 + k4 * 4);
      acc[r][0] += a.x * w0.x + a.y * w1.x + a.z * w2.x + a.w * w3.x;
      acc[r][1] += a.x * w0.y + a.y * w1.y + a.z * w2.y + a.w * w3.y;
      acc[r][2] += a.x * w0.z + a.y * w1.z + a.z * w2.z + a.w * w3.z;
      acc[r][3] += a.x * w0.w + a.y * w1.w + a.z * w2.w + a.w * w3.w;
    }
  }

  // ---- Epilogue: +b2 (+h) -> relu -> +x; write fp32 state AND bf16 shadow
  float4 b2v = *(const float4*)(b2 + cg * 4);
  float4* xo4 = (float4*)xout;
  ushort4* xho4 = (ushort4*)xh_out;
#pragma unroll
  for (int r = 0; r < 4; ++r) {
    int row = base + rg * 4 + r;
    if (row < n) {
      float ox = acc[r][0] + b2v.x;
      float oy = acc[r][1] + b2v.y;
      float oz = acc[r][2] + b2v.z;
      float ow = acc[r][3] + b2v.w;
      if (addH) {
        ox += hsnap[r].x; oy += hsnap[r].y; oz += hsnap[r].z; ow += hsnap[r].w;
      }
      ox = fmaxf(ox, 0.f); oy = fmaxf(oy, 0.f); oz = fmaxf(oz, 0.f); ow = fmaxf(ow, 0.f);
      float4 xv = x4[row * 32 + cg];
      float4 o;
      o.x = ox + xv.x; o.y = oy + xv.y; o.z = oz + xv.z; o.w = ow + xv.w;
      xo4[row * 32 + cg] = o;
      ushort4 ob;
      ob.x = f2bf(o.x); ob.y = f2bf(o.y); ob.z = f2bf(o.z); ob.w = f2bf(o.w);
      xho4[row * 32 + cg] = ob;
    }
  }
}

// ---------------- pooling (batch is sorted) ----------------

__global__ __launch_bounds__(128) void pool_kernel(const float* __restrict__ x,
                                                   const int* __restrict__ batch,
                                                   float* __restrict__ pool,
                                                   int* __restrict__ gcnt, int n) {
  const int CH = 512;
  int c = threadIdx.x;
  int n0 = blockIdx.x * CH;
  if (n0 >= n) return;
  int n1 = n0 + CH; if (n1 > n) n1 = n;
  float acc = 0.f;
  int g = batch[n0];
  int cl = 0;
  for (int i = n0; i < n1; ++i) {
    int gi = batch[i];
    if (gi != g) {
      atomicAdd(&pool[g * 128 + c], acc);
      if (c == 0) atomicAdd(&gcnt[g], cl);
      acc = 0.f; cl = 0; g = gi;
    }
    acc += x[i * 128 + c];
    cl++;
  }
  atomicAdd(&pool[g * 128 + c], acc);
  if (c == 0) atomicAdd(&gcnt[g], cl);
}

// ---------------- classifier: one block per graph ----------------

__global__ __launch_bounds__(128) void classifier_kernel(const float* __restrict__ pool,
                                                         const int* __restrict__ gcnt,
                                                         const float* __restrict__ Wc1,
                                                         const float* __restrict__ bc1,
                                                         const float* __restrict__ Wc2,
                                                         const float* __restrict__ bc2,
                                                         float* __restrict__ out) {
  __shared__ float prow[128];
  __shared__ float hid[128];
  int g = blockIdx.x;
  int c = threadIdx.x;
  float cf = (float)gcnt[g];
  if (cf < 1.f) cf = 1.f;
  prow[c] = pool[g * 128 + c] / cf;
  __syncthreads();
  float a = bc1[c];
  for (int k = 0; k < 128; ++k) a += prow[k] * Wc1[k * 128 + c];
  hid[c] = fmaxf(a, 0.f);
  __syncthreads();
  if (c < 2) {
    float a2 = bc2[c];
    for (int k = 0; k < 128; ++k) a2 += hid[k] * Wc2[k * 2 + c];
    out[g * 2 + c] = a2;
  }
}

// ---------------- launch ----------------

extern "C" void kernel_launch(void* const* d_in, const int* in_sizes, int n_in,
                              void* d_out, int out_size, void* d_ws, size_t ws_size,
                              hipStream_t stream) {
  const float* x_in = (const float*)d_in[0];
  const int* edge_index = (const int*)d_in[1];
  const int* batch = (const int*)d_in[2];
  const float* eps = (const float*)d_in[3];
  const float* W1 = (const float*)d_in[4];
  const float* b1 = (const float*)d_in[5];
  const float* W2 = (const float*)d_in[6];
  const float* b2 = (const float*)d_in[7];
  const float* Wc1 = (const float*)d_in[8];
  const float* bc1 = (const float*)d_in[9];
  const float* Wc2 = (const float*)d_in[10];
  const float* bc2 = (const float*)d_in[11];
  float* out = (float*)d_out;

  const int N = N_NODES, E = N_EDGES;
  const int* src = edge_index;
  const int* dst = edge_index + E;

  // workspace layout: one fp32 state + two bf16 shadows
  float* xa = (float*)d_ws;                        // N*128 floats (fp32 state, in-place)
  ushort_t* xha = (ushort_t*)(xa + (size_t)N * 128);   // N*128 bf16
  ushort_t* xhb = xha + (size_t)N * 128;               // N*128 bf16
  int* deg = (int*)(xhb + (size_t)N * 128);        // N
  int* rs = deg + N;                               // N+1
  int* cur = rs + (N + 1);                         // N
  int* csr = cur + N;                              // E
  float* pool = (float*)(csr + E);                 // 64*128
  int* gcnt = (int*)(pool + NUM_GRAPHS * 128);     // 64
  int* psum = gcnt + NUM_GRAPHS;                   // SCAN_BLOCKS
  int* poff = psum + SCAN_BLOCKS;                  // SCAN_BLOCKS

  hipMemsetAsync(deg, 0, N * sizeof(int), stream);

  // CSR build
  count_deg_kernel<<<(E + 255) / 256, 256, 0, stream>>>(dst, deg, E);
  block_sum_kernel<<<SCAN_BLOCKS, 256, 0, stream>>>(deg, psum, N);
  scan_partials_kernel<<<1, 512, 0, stream>>>(psum, poff, SCAN_BLOCKS);
  write_rs_kernel<<<SCAN_BLOCKS, 256, 0, stream>>>(deg, poff, rs, cur, N);
  fill_csr_kernel<<<(E + 255) / 256, 256, 0, stream>>>(src, dst, cur, csr, E);

  // bf16 shadow of the input
  cast_bf16_kernel<<<(N * 32 + 255) / 256, 256, 0, stream>>>(x_in, xha, N * 32);

  // layers: fp32 state in-place in xa (layer 0 reads input buffer); shadow ping-pongs
  const int NB = N / WROWS;  // 12500 one-wave blocks
  for (int i = 0; i < NUM_LAYERS; ++i) {
    const float* xi = (i == 0) ? x_in : xa;
    const ushort_t* gin = (i % 2 == 0) ? xha : xhb;
    ushort_t* gout = (i % 2 == 0) ? xhb : xha;
    layer_kernel<<<NB, 64, 0, stream>>>(xi, xa, gin, gout, rs, csr, eps, i,
                                        W1 + (size_t)i * 128 * 128, b1 + (size_t)i * 128,
                                        W2 + (size_t)i * 128 * 128, b2 + (size_t)i * 128,
                                        N, i > 0 ? 1 : 0);
  }

  // pooling + classifier
  hipMemsetAsync(pool, 0, NUM_GRAPHS * 128 * sizeof(float), stream);
  hipMemsetAsync(gcnt, 0, NUM_GRAPHS * sizeof(int), stream);
  pool_kernel<<<(N + 511) / 512, 128, 0, stream>>>(xa, batch, pool, gcnt, N);
  classifier_kernel<<<NUM_GRAPHS, 128, 0, stream>>>(pool, gcnt, Wc1, bc1, Wc2, bc2, out);
}